// Round 8
// baseline (270.270 us; speedup 1.0000x reference)
//
#include <hip/hip_runtime.h>
#include <hip/hip_bf16.h>

typedef short s16x8 __attribute__((ext_vector_type(8)));
typedef float f32x16 __attribute__((ext_vector_type(16)));

namespace {
constexpr int kB = 16;
constexpr int kD = 256;
constexpr int kHW = 16384;
constexpr int kM = 4096;
constexpr int kN = kB * kM;              // 65536 samples
constexpr int kWin = 1024;               // columns per block
constexpr int kNBlk = kB * (kHW / kWin); // 256 blocks
constexpr int kKT = 32;                  // K-tile columns
constexpr int kNIter = kWin / kKT;       // 32 iterations
constexpr float kLam = 0.005f;

// round-to-nearest-even f32 -> bf16 bits
__device__ __forceinline__ unsigned short f2bf(float f) {
    union { float f; unsigned u; } x{f};
    const unsigned r = x.u + 0x7FFFu + ((x.u >> 16) & 1u);
    return (unsigned short)(r >> 16);
}
}

// ---------------------------------------------------------------------------
// Kernel 1: per-b histogram of flat_idx -> counts c[b][p].
// ---------------------------------------------------------------------------
__global__ __launch_bounds__(256) void count_kernel(
    const int* __restrict__ flat_idx, int* __restrict__ cnt)
{
    __shared__ int h[kHW];   // 64 KiB
    const int t = threadIdx.x;
    const int b = blockIdx.x;
    for (int i = t; i < kHW; i += 256) h[i] = 0;
    __syncthreads();
    const int* bi = flat_idx + b * kM;
    for (int i = t; i < kM; i += 256) atomicAdd(&h[bi[i]], 1);
    __syncthreads();
    int* dst = cnt + b * kHW;
    for (int i = t; i < kHW; i += 256) dst[i] = h[i];
}

// ---------------------------------------------------------------------------
// Kernel 2: fused stream + weighted Gram + stats.
// v2 pipeline: ping-pong register sets S0/S1 + single barrier per iter.
// iter kt: { CONVERT(kt+1) from S[(kt+1)&1] -> buf[(kt+1)&1];
//            LOAD(kt+3) -> S[(kt+1)&1];  MFMA(kt, buf[kt&1]); bar }
// Load->use slack ~2 iterations (HBM latency fully hidden); MFMA (matrix
// pipe) co-issues with convert VALU in the same region (m114 overlap).
// ---------------------------------------------------------------------------
__global__ __launch_bounds__(512, 2) void fused_gram_kernel(
    const float* __restrict__ z, const float* __restrict__ zp,
    const int* __restrict__ cnt,
    float* __restrict__ partial, float* __restrict__ statsPart)
{
    __shared__ char smem[65536];   // buf0 @0: A[16KB] B[16KB]; buf1 @32KB

    const int bx = blockIdx.x;
    const int b = bx & (kB - 1);
    const int win0 = (bx >> 4) * kWin;
    const int t = threadIdx.x;
    const int w = t >> 6, lane = t & 63, l31 = lane & 31, half = lane >> 5;
    const int wr = w >> 2;          // 0..1  row block of 128
    const int wc = w & 3;           // 0..3  col block of 64
    const int rbase = t >> 3;       // 0..63 staging row within 64-row group
    const int cg = t & 7;           // 0..7  staging col group (4 f32)

    const float* zb  = z  + (size_t)b * kD * kHW;
    const float* zpb = zp + (size_t)b * kD * kHW;
    const int* cb = cnt + b * kHW;

    f32x16 acc[4][2];
#pragma unroll
    for (int i = 0; i < 4; ++i)
#pragma unroll
        for (int j = 0; j < 2; ++j)
#pragma unroll
            for (int r = 0; r < 16; ++r) acc[i][j][r] = 0.f;

    float sA[4], ssA[4], sB[4], ssB[4];
#pragma unroll
    for (int q = 0; q < 4; ++q) { sA[q] = ssA[q] = sB[q] = ssB[q] = 0.f; }

    // two register sets (static names -> stays in VGPRs)
    float4 va0[4], vb0[4], va1[4], vb1[4];
    int4 ci0, ci1;

#define LOAD_SET(S, kt)                                                     \
    {                                                                       \
        const int base_ = win0 + (kt) * kKT + cg * 4;                       \
        _Pragma("unroll")                                                   \
        for (int q = 0; q < 4; ++q) {                                       \
            const int row_ = 64 * q + rbase;                                \
            va##S[q] = *(const float4*)(zb  + (size_t)row_ * kHW + base_);  \
            vb##S[q] = *(const float4*)(zpb + (size_t)row_ * kHW + base_);  \
        }                                                                   \
        ci##S = *(const int4*)(cb + base_);                                 \
    }

#define CONV_SET(S, buf)                                                    \
    {                                                                       \
        char* As_ = smem + (buf) * 32768;                                   \
        char* Bs_ = As_ + 16384;                                            \
        const float cf_[4] = {(float)ci##S.x, (float)ci##S.y,               \
                              (float)ci##S.z, (float)ci##S.w};              \
        _Pragma("unroll")                                                   \
        for (int q = 0; q < 4; ++q) {                                       \
            const int row_ = 64 * q + rbase;                                \
            const float a_[4]  = {va##S[q].x, va##S[q].y, va##S[q].z, va##S[q].w}; \
            const float bb_[4] = {vb##S[q].x, vb##S[q].y, vb##S[q].z, vb##S[q].w}; \
            ushort4 pa_, pb_;                                               \
            unsigned short* pav_ = (unsigned short*)&pa_;                   \
            unsigned short* pbv_ = (unsigned short*)&pb_;                   \
            _Pragma("unroll")                                               \
            for (int j = 0; j < 4; ++j) {                                   \
                const float a2_ = a_[j] * a_[j];                            \
                const float b2_ = bb_[j] * bb_[j];                          \
                const float wb_ = cf_[j] * bb_[j];                          \
                sA[q] = fmaf(cf_[j], a_[j], sA[q]);                         \
                ssA[q] = fmaf(cf_[j], a2_, ssA[q]);                         \
                sB[q] = fmaf(cf_[j], bb_[j], sB[q]);                        \
                ssB[q] = fmaf(cf_[j], b2_, ssB[q]);                         \
                pav_[j] = f2bf(a_[j]);                                      \
                pbv_[j] = f2bf(wb_);                                        \
            }                                                               \
            const int off_ = row_ * 64 + (((cg >> 1) ^ ((row_ >> 1) & 3)) << 4) \
                           + ((cg & 1) << 3);                               \
            *(ushort4*)(As_ + off_) = pa_;                                  \
            *(ushort4*)(Bs_ + off_) = pb_;                                  \
        }                                                                   \
    }

    auto MFMA_STEP = [&](int buf) {
        const char* As = smem + buf * 32768;
        const char* Bs = As + 16384;
#pragma unroll
        for (int ks = 0; ks < 2; ++ks) {
            s16x8 af[4], bfr[2];
#pragma unroll
            for (int rt = 0; rt < 4; ++rt) {
                const int row = 128 * wr + 32 * rt + l31;
                const int o = (2 * ks + half) ^ ((row >> 1) & 3);
                af[rt] = *(const s16x8*)(As + row * 64 + o * 16);
            }
#pragma unroll
            for (int ct = 0; ct < 2; ++ct) {
                const int row = 64 * wc + 32 * ct + l31;
                const int o = (2 * ks + half) ^ ((row >> 1) & 3);
                bfr[ct] = *(const s16x8*)(Bs + row * 64 + o * 16);
            }
#pragma unroll
            for (int rt = 0; rt < 4; ++rt)
#pragma unroll
                for (int ct = 0; ct < 2; ++ct)
                    acc[rt][ct] = __builtin_amdgcn_mfma_f32_32x32x16_bf16(
                        af[rt], bfr[ct], acc[rt][ct], 0, 0, 0);
        }
    };

    // Prologue: tile0 -> buf0 via S0; preload tiles 1 (S1) and 2 (S0).
    LOAD_SET(0, 0)
    CONV_SET(0, 0)
    LOAD_SET(1, 1)
    LOAD_SET(0, 2)
    __syncthreads();

    // Main loop, unrolled x2 for static register-set names.
    // even iter kt:   CONV S1 -> buf1 (tile kt+1), LOAD(kt+3)->S1, MFMA(buf0)
    // odd  iter kt+1: CONV S0 -> buf0 (tile kt+2), LOAD(kt+4)->S0, MFMA(buf1)
    for (int kt = 0; kt < kNIter; kt += 2) {
        CONV_SET(1, 1)                       // tile kt+1 (kt<=30 -> valid)
        if (kt + 3 < kNIter) LOAD_SET(1, kt + 3)
        MFMA_STEP(0);                        // tile kt
        __syncthreads();

        if (kt + 2 < kNIter) CONV_SET(0, 0)  // tile kt+2
        if (kt + 4 < kNIter) LOAD_SET(0, kt + 4)
        MFMA_STEP(1);                        // tile kt+1
        __syncthreads();
    }

    // 256x256 partial Gram
    float* out = partial + (size_t)bx * (kD * kD);
#pragma unroll
    for (int rt = 0; rt < 4; ++rt)
#pragma unroll
        for (int ct = 0; ct < 2; ++ct)
#pragma unroll
            for (int r = 0; r < 16; ++r) {
                const int row = 128 * wr + 32 * rt + (r & 3) + 8 * (r >> 2) + 4 * half;
                const int col = 64 * wc + 32 * ct + l31;
                out[row * kD + col] = acc[rt][ct][r];
            }

    // stats partial reduce via (dead) LDS: sd[256 rows][8 cg][4 kinds] = 32KB
    float* sd = (float*)smem;
#pragma unroll
    for (int q = 0; q < 4; ++q) {
        const int row = 64 * q + rbase;
        float* p = sd + (row * 8 + cg) * 4;
        p[0] = sA[q]; p[1] = ssA[q]; p[2] = sB[q]; p[3] = ssB[q];
    }
    __syncthreads();
    {
        const int row = t >> 1;
        const int pair = t & 1;
        float a0 = 0.f, a1 = 0.f;
#pragma unroll
        for (int g = 0; g < 8; ++g) {
            a0 += sd[(row * 8 + g) * 4 + 2 * pair];
            a1 += sd[(row * 8 + g) * 4 + 2 * pair + 1];
        }
        float* p = statsPart + ((size_t)bx * kD + row) * 4;
        p[2 * pair] = a0;
        p[2 * pair + 1] = a1;
    }
#undef LOAD_SET
#undef CONV_SET
}

// ---------------------------------------------------------------------------
// Kernel 3: reduce partial Grams -> G; also reduce statsPart -> statsRed.
// ---------------------------------------------------------------------------
__global__ __launch_bounds__(256) void reduce_gram_kernel(
    const float* __restrict__ partial, const float* __restrict__ statsPart,
    float* __restrict__ G, float* __restrict__ statsRed)
{
    const int d = blockIdx.x;
    const int e = threadIdx.x;
    float s = 0.f;
#pragma unroll 8
    for (int c = 0; c < kNBlk; ++c)
        s += partial[(size_t)c * (kD * kD) + d * kD + e];
    G[d * kD + e] = s;

    // stats: thread e takes source-block e, 4 floats of row d
    const float4 v = *(const float4*)(statsPart + ((size_t)e * kD + d) * 4);
    float x0 = v.x, x1 = v.y, x2 = v.z, x3 = v.w;
#pragma unroll
    for (int o = 32; o; o >>= 1) {
        x0 += __shfl_down(x0, o);
        x1 += __shfl_down(x1, o);
        x2 += __shfl_down(x2, o);
        x3 += __shfl_down(x3, o);
    }
    __shared__ float r[4][4];
    if ((e & 63) == 0) {
        r[e >> 6][0] = x0; r[e >> 6][1] = x1;
        r[e >> 6][2] = x2; r[e >> 6][3] = x3;
    }
    __syncthreads();
    if (e < 4) {
        statsRed[d * 4 + e] = r[0][e] + r[1][e] + r[2][e] + r[3][e];
    }
}

// ---------------------------------------------------------------------------
// Kernel 4: final loss (single block).
// ---------------------------------------------------------------------------
__global__ __launch_bounds__(256) void loss_kernel(
    const float* __restrict__ G, const float* __restrict__ statsRed,
    float* __restrict__ out)
{
    __shared__ float muA[kD], isA[kD], muB[kD], isB[kD];
    const int t = threadIdx.x;
    const float4 v = *(const float4*)(statsRed + t * 4);
    const float n = (float)kN;
    const float mA = v.x / n, mB = v.z / n;
    const float vA = (v.y - n * mA * mA) / (n - 1.f);
    const float vB = (v.w - n * mB * mB) / (n - 1.f);
    const float sdA = fmaxf(sqrtf(fmaxf(vA, 0.f)), 1e-6f);
    const float sdB = fmaxf(sqrtf(fmaxf(vB, 0.f)), 1e-6f);
    muA[t] = mA; isA[t] = 1.f / sdA;
    muB[t] = mB; isB[t] = 1.f / sdB;
    __syncthreads();

    float acc = 0.f;
    for (int d = 0; d < kD; ++d) {
        const int e = t;
        const float c = (G[d * kD + e] / n - muA[d] * muB[e]) * isA[d] * isB[e];
        if (d == e) { const float u = 1.f - c; acc += u * u; }
        else        { acc += kLam * c * c; }
    }
#pragma unroll
    for (int o = 32; o; o >>= 1) acc += __shfl_down(acc, o);
    __shared__ float r[4];
    if ((t & 63) == 0) r[t >> 6] = acc;
    __syncthreads();
    if (t == 0) out[0] = r[0] + r[1] + r[2] + r[3];
}

// ---------------------------------------------------------------------------
extern "C" void kernel_launch(void* const* d_in, const int* in_sizes, int n_in,
                              void* d_out, int out_size, void* d_ws, size_t ws_size,
                              hipStream_t stream) {
    const float* z  = (const float*)d_in[0];
    const float* zp = (const float*)d_in[1];
    const int* flat_idx = (const int*)d_in[2];
    float* out = (float*)d_out;

    char* ws = (char*)d_ws;
    // ws layout:
    //   [0, 1MB)     counts  int [16][16384]
    //   [1MB, 2MB)   statsPart f32 [256][256][4]
    //   [2MB, +4K)   statsRed f32 [256][4]
    //   [2MB+64K, +256K) G f32 [256][256]
    //   [16MB, 80MB) partial f32 [256][256][256]
    int* cnt = (int*)ws;
    float* statsPart = (float*)(ws + (size_t)1 * 1024 * 1024);
    float* statsRed  = (float*)(ws + (size_t)2 * 1024 * 1024);
    float* G = (float*)(ws + (size_t)2 * 1024 * 1024 + 64 * 1024);
    float* partial = (float*)(ws + (size_t)16 * 1024 * 1024);

    count_kernel<<<kB, 256, 0, stream>>>(flat_idx, cnt);
    fused_gram_kernel<<<kNBlk, 512, 0, stream>>>(z, zp, cnt, partial, statsPart);
    reduce_gram_kernel<<<kD, 256, 0, stream>>>(partial, statsPart, G, statsRed);
    loss_kernel<<<1, 256, 0, stream>>>(G, statsRed, out);
}

// Round 9
// 209.974 us; speedup vs baseline: 1.2872x; 1.2872x over previous
//
#include <hip/hip_runtime.h>
#include <hip/hip_bf16.h>

typedef short s16x8 __attribute__((ext_vector_type(8)));
typedef float f32x16 __attribute__((ext_vector_type(16)));

namespace {
constexpr int kB = 16;
constexpr int kD = 256;
constexpr int kHW = 16384;
constexpr int kM = 4096;
constexpr int kN = kB * kM;              // 65536 samples
constexpr int kWin = 1024;               // columns per block
constexpr int kNBlk = kB * (kHW / kWin); // 256 blocks
constexpr int kKT = 16;                  // K-tile columns (small => small bursts)
constexpr int kNIter = kWin / kKT;       // 64 iterations
constexpr float kLam = 0.005f;

// round-to-nearest-even f32 -> bf16 bits
__device__ __forceinline__ unsigned short f2bf(float f) {
    union { float f; unsigned u; } x{f};
    const unsigned r = x.u + 0x7FFFu + ((x.u >> 16) & 1u);
    return (unsigned short)(r >> 16);
}
}

// ---------------------------------------------------------------------------
// Kernel 1: per-b histogram of flat_idx -> counts c[b][p].
// ---------------------------------------------------------------------------
__global__ __launch_bounds__(256) void count_kernel(
    const int* __restrict__ flat_idx, int* __restrict__ cnt)
{
    __shared__ int h[kHW];   // 64 KiB
    const int t = threadIdx.x;
    const int b = blockIdx.x;
    for (int i = t; i < kHW; i += 256) h[i] = 0;
    __syncthreads();
    const int* bi = flat_idx + b * kM;
    for (int i = t; i < kM; i += 256) atomicAdd(&h[bi[i]], 1);
    __syncthreads();
    int* dst = cnt + b * kHW;
    for (int i = t; i < kHW; i += 256) dst[i] = h[i];
}

// ---------------------------------------------------------------------------
// Kernel 2: fused stream + weighted Gram + stats.
// kKT=16 ping-pong: 2 register sets of 16 VGPR each (no spill; acc=128 AGPR),
// 2 bursts of 32KB in flight -> HBM transfer overlaps convert+MFMA.
// LDS per buffer: A[2][256][16B] (fragment order, lane-linear ds_read_b128,
// conflict-free) + B same; 2 buffers = 32 KB.  One barrier per iteration.
// ---------------------------------------------------------------------------
__global__ __launch_bounds__(512, 2) void fused_gram_kernel(
    const float* __restrict__ z, const float* __restrict__ zp,
    const int* __restrict__ cnt,
    float* __restrict__ partial, float* __restrict__ statsPart)
{
    __shared__ char smem[32768];   // buf0 @0 (A 8K | B 8K), buf1 @16K

    const int bx = blockIdx.x;
    const int b = bx & (kB - 1);
    const int win0 = (bx >> 4) * kWin;
    const int t = threadIdx.x;
    const int w = t >> 6, lane = t & 63, l31 = lane & 31, half = lane >> 5;
    const int wr = w >> 2;          // 0..1  row block of 128
    const int wc = w & 3;           // 0..3  col block of 64
    const int rbase = t >> 2;       // 0..127 staging row
    const int cg = t & 3;           // 0..3   staging col group (4 f32)

    const float* zb  = z  + (size_t)b * kD * kHW;
    const float* zpb = zp + (size_t)b * kD * kHW;
    const int* cb = cnt + b * kHW;

    f32x16 acc[4][2];
#pragma unroll
    for (int i = 0; i < 4; ++i)
#pragma unroll
        for (int j = 0; j < 2; ++j)
#pragma unroll
            for (int r = 0; r < 16; ++r) acc[i][j][r] = 0.f;

    float sA[2], ssA[2], sB[2], ssB[2];
#pragma unroll
    for (int q = 0; q < 2; ++q) { sA[q] = ssA[q] = sB[q] = ssB[q] = 0.f; }

    // two register sets (static names -> stay in VGPRs)
    float4 va0[2], vb0[2], va1[2], vb1[2];
    int4 ci0, ci1;

#define LOAD_SET(S, kt)                                                     \
    {                                                                       \
        const int base_ = win0 + (kt) * kKT + cg * 4;                       \
        _Pragma("unroll")                                                   \
        for (int q = 0; q < 2; ++q) {                                       \
            const int row_ = rbase + 128 * q;                               \
            va##S[q] = *(const float4*)(zb  + (size_t)row_ * kHW + base_);  \
            vb##S[q] = *(const float4*)(zpb + (size_t)row_ * kHW + base_);  \
        }                                                                   \
        ci##S = *(const int4*)(cb + base_);                                 \
    }

    // LDS fragment-order write: element (row, k) of A at
    //   As + ((k>>3)*256 + row)*16 + (k&7)*2 ; thread's 4 cols are k=cg*4+j
    //   => one 8B write at slot (cg&1).  B identical at +8KB.
#define CONV_SET(S, buf)                                                    \
    {                                                                       \
        char* As_ = smem + (buf) * 16384;                                   \
        char* Bs_ = As_ + 8192;                                             \
        const float cf_[4] = {(float)ci##S.x, (float)ci##S.y,               \
                              (float)ci##S.z, (float)ci##S.w};              \
        _Pragma("unroll")                                                   \
        for (int q = 0; q < 2; ++q) {                                       \
            const int row_ = rbase + 128 * q;                               \
            const float a_[4]  = {va##S[q].x, va##S[q].y, va##S[q].z, va##S[q].w}; \
            const float bb_[4] = {vb##S[q].x, vb##S[q].y, vb##S[q].z, vb##S[q].w}; \
            ushort4 pa_, pb_;                                               \
            unsigned short* pav_ = (unsigned short*)&pa_;                   \
            unsigned short* pbv_ = (unsigned short*)&pb_;                   \
            _Pragma("unroll")                                               \
            for (int j = 0; j < 4; ++j) {                                   \
                const float a2_ = a_[j] * a_[j];                            \
                const float b2_ = bb_[j] * bb_[j];                          \
                const float wb_ = cf_[j] * bb_[j];                          \
                sA[q] = fmaf(cf_[j], a_[j], sA[q]);                         \
                ssA[q] = fmaf(cf_[j], a2_, ssA[q]);                         \
                sB[q] = fmaf(cf_[j], bb_[j], sB[q]);                        \
                ssB[q] = fmaf(cf_[j], b2_, ssB[q]);                         \
                pav_[j] = f2bf(a_[j]);                                      \
                pbv_[j] = f2bf(wb_);                                        \
            }                                                               \
            const int off_ = (((cg >> 1) * 256 + row_) << 4) + ((cg & 1) << 3); \
            *(unsigned long long*)(As_ + off_) = *(unsigned long long*)&pa_; \
            *(unsigned long long*)(Bs_ + off_) = *(unsigned long long*)&pb_; \
        }                                                                   \
    }

    auto MFMA_STEP = [&](int buf) {
        const char* As = smem + buf * 16384;
        const char* Bs = As + 8192;
        s16x8 af[4], bfr[2];
#pragma unroll
        for (int rt = 0; rt < 4; ++rt) {
            const int row = 128 * wr + 32 * rt + l31;
            af[rt] = *(const s16x8*)(As + ((half * 256 + row) << 4));
        }
#pragma unroll
        for (int ct = 0; ct < 2; ++ct) {
            const int row = 64 * wc + 32 * ct + l31;
            bfr[ct] = *(const s16x8*)(Bs + ((half * 256 + row) << 4));
        }
#pragma unroll
        for (int rt = 0; rt < 4; ++rt)
#pragma unroll
            for (int ct = 0; ct < 2; ++ct)
                acc[rt][ct] = __builtin_amdgcn_mfma_f32_32x32x16_bf16(
                    af[rt], bfr[ct], acc[rt][ct], 0, 0, 0);
    };

    // Prologue: tile0 -> buf0 via S0; preload tile1 (S1), tile2 (S0).
    LOAD_SET(0, 0)
    CONV_SET(0, 0)
    LOAD_SET(1, 1)
    LOAD_SET(0, 2)
    __syncthreads();

    // Main loop unrolled x2 (static register-set names).
    for (int kt = 0; kt < kNIter; kt += 2) {
        CONV_SET(1, 1)                       // tile kt+1 (kt<=62 -> valid)
        if (kt + 3 < kNIter) LOAD_SET(1, kt + 3)
        MFMA_STEP(0);                        // tile kt
        __syncthreads();

        if (kt + 2 < kNIter) CONV_SET(0, 0)  // tile kt+2
        if (kt + 4 < kNIter) LOAD_SET(0, kt + 4)
        MFMA_STEP(1);                        // tile kt+1
        __syncthreads();
    }

    // 256x256 partial Gram
    float* out = partial + (size_t)bx * (kD * kD);
#pragma unroll
    for (int rt = 0; rt < 4; ++rt)
#pragma unroll
        for (int ct = 0; ct < 2; ++ct)
#pragma unroll
            for (int r = 0; r < 16; ++r) {
                const int row = 128 * wr + 32 * rt + (r & 3) + 8 * (r >> 2) + 4 * half;
                const int col = 64 * wc + 32 * ct + l31;
                out[row * kD + col] = acc[rt][ct][r];
            }

    // stats partial reduce via (dead) LDS: sd[256 rows][4 cg][4 kinds] = 16KB
    float* sd = (float*)smem;
#pragma unroll
    for (int q = 0; q < 2; ++q) {
        const int row = rbase + 128 * q;
        float* p = sd + (row * 4 + cg) * 4;
        p[0] = sA[q]; p[1] = ssA[q]; p[2] = sB[q]; p[3] = ssB[q];
    }
    __syncthreads();
    {
        const int row = t >> 1;
        const int pair = t & 1;
        float a0 = 0.f, a1 = 0.f;
#pragma unroll
        for (int g = 0; g < 4; ++g) {
            a0 += sd[(row * 4 + g) * 4 + 2 * pair];
            a1 += sd[(row * 4 + g) * 4 + 2 * pair + 1];
        }
        float* p = statsPart + ((size_t)bx * kD + row) * 4;
        p[2 * pair] = a0;
        p[2 * pair + 1] = a1;
    }
#undef LOAD_SET
#undef CONV_SET
}

// ---------------------------------------------------------------------------
// Kernel 3: reduce partial Grams -> G; also reduce statsPart -> statsRed.
// ---------------------------------------------------------------------------
__global__ __launch_bounds__(256) void reduce_gram_kernel(
    const float* __restrict__ partial, const float* __restrict__ statsPart,
    float* __restrict__ G, float* __restrict__ statsRed)
{
    const int d = blockIdx.x;
    const int e = threadIdx.x;
    float s = 0.f;
#pragma unroll 8
    for (int c = 0; c < kNBlk; ++c)
        s += partial[(size_t)c * (kD * kD) + d * kD + e];
    G[d * kD + e] = s;

    // stats: thread e takes source-block e, 4 floats of row d
    const float4 v = *(const float4*)(statsPart + ((size_t)e * kD + d) * 4);
    float x0 = v.x, x1 = v.y, x2 = v.z, x3 = v.w;
#pragma unroll
    for (int o = 32; o; o >>= 1) {
        x0 += __shfl_down(x0, o);
        x1 += __shfl_down(x1, o);
        x2 += __shfl_down(x2, o);
        x3 += __shfl_down(x3, o);
    }
    __shared__ float r[4][4];
    if ((e & 63) == 0) {
        r[e >> 6][0] = x0; r[e >> 6][1] = x1;
        r[e >> 6][2] = x2; r[e >> 6][3] = x3;
    }
    __syncthreads();
    if (e < 4) {
        statsRed[d * 4 + e] = r[0][e] + r[1][e] + r[2][e] + r[3][e];
    }
}

// ---------------------------------------------------------------------------
// Kernel 4: final loss (single block).
// ---------------------------------------------------------------------------
__global__ __launch_bounds__(256) void loss_kernel(
    const float* __restrict__ G, const float* __restrict__ statsRed,
    float* __restrict__ out)
{
    __shared__ float muA[kD], isA[kD], muB[kD], isB[kD];
    const int t = threadIdx.x;
    const float4 v = *(const float4*)(statsRed + t * 4);
    const float n = (float)kN;
    const float mA = v.x / n, mB = v.z / n;
    const float vA = (v.y - n * mA * mA) / (n - 1.f);
    const float vB = (v.w - n * mB * mB) / (n - 1.f);
    const float sdA = fmaxf(sqrtf(fmaxf(vA, 0.f)), 1e-6f);
    const float sdB = fmaxf(sqrtf(fmaxf(vB, 0.f)), 1e-6f);
    muA[t] = mA; isA[t] = 1.f / sdA;
    muB[t] = mB; isB[t] = 1.f / sdB;
    __syncthreads();

    float acc = 0.f;
    for (int d = 0; d < kD; ++d) {
        const int e = t;
        const float c = (G[d * kD + e] / n - muA[d] * muB[e]) * isA[d] * isB[e];
        if (d == e) { const float u = 1.f - c; acc += u * u; }
        else        { acc += kLam * c * c; }
    }
#pragma unroll
    for (int o = 32; o; o >>= 1) acc += __shfl_down(acc, o);
    __shared__ float r[4];
    if ((t & 63) == 0) r[t >> 6] = acc;
    __syncthreads();
    if (t == 0) out[0] = r[0] + r[1] + r[2] + r[3];
}

// ---------------------------------------------------------------------------
extern "C" void kernel_launch(void* const* d_in, const int* in_sizes, int n_in,
                              void* d_out, int out_size, void* d_ws, size_t ws_size,
                              hipStream_t stream) {
    const float* z  = (const float*)d_in[0];
    const float* zp = (const float*)d_in[1];
    const int* flat_idx = (const int*)d_in[2];
    float* out = (float*)d_out;

    char* ws = (char*)d_ws;
    // ws layout:
    //   [0, 1MB)     counts  int [16][16384]
    //   [1MB, 2MB)   statsPart f32 [256][256][4]
    //   [2MB, +4K)   statsRed f32 [256][4]
    //   [2MB+64K, +256K) G f32 [256][256]
    //   [16MB, 80MB) partial f32 [256][256][256]
    int* cnt = (int*)ws;
    float* statsPart = (float*)(ws + (size_t)1 * 1024 * 1024);
    float* statsRed  = (float*)(ws + (size_t)2 * 1024 * 1024);
    float* G = (float*)(ws + (size_t)2 * 1024 * 1024 + 64 * 1024);
    float* partial = (float*)(ws + (size_t)16 * 1024 * 1024);

    count_kernel<<<kB, 256, 0, stream>>>(flat_idx, cnt);
    fused_gram_kernel<<<kNBlk, 512, 0, stream>>>(z, zp, cnt, partial, statsPart);
    reduce_gram_kernel<<<kD, 256, 0, stream>>>(partial, statsPart, G, statsRed);
    loss_kernel<<<1, 256, 0, stream>>>(G, statsRed, out);
}

// Round 10
// 207.061 us; speedup vs baseline: 1.3053x; 1.0141x over previous
//
#include <hip/hip_runtime.h>
#include <hip/hip_bf16.h>

typedef short s16x8 __attribute__((ext_vector_type(8)));
typedef float f32x16 __attribute__((ext_vector_type(16)));

namespace {
constexpr int kB = 16;
constexpr int kD = 256;
constexpr int kHW = 16384;
constexpr int kM = 4096;
constexpr int kN = kB * kM;              // 65536 samples
constexpr int kWin = 1024;               // columns per block
constexpr int kNBlk = kB * (kHW / kWin); // 256 blocks
constexpr int kKT = 16;                  // K-tile columns
constexpr int kNIter = kWin / kKT;       // 64 iterations
constexpr float kLam = 0.005f;

// round-to-nearest-even f32 -> bf16 bits
__device__ __forceinline__ unsigned short f2bf(float f) {
    union { float f; unsigned u; } x{f};
    const unsigned r = x.u + 0x7FFFu + ((x.u >> 16) & 1u);
    return (unsigned short)(r >> 16);
}
}

// Counted barrier: flush LDS writes (cross-wave visibility) but do NOT
// drain vmcnt -- global prefetches stay in flight across the barrier.
// (__syncthreads would emit s_waitcnt vmcnt(0) and collapse the pipeline.)
#define BAR_SOFT()                                            \
    do {                                                      \
        asm volatile("s_waitcnt lgkmcnt(0)" ::: "memory");    \
        __builtin_amdgcn_s_barrier();                         \
    } while (0)

// ---------------------------------------------------------------------------
// Kernel 1: per-b histogram of flat_idx -> counts c[b][p].
// ---------------------------------------------------------------------------
__global__ __launch_bounds__(256) void count_kernel(
    const int* __restrict__ flat_idx, int* __restrict__ cnt)
{
    __shared__ int h[kHW];   // 64 KiB
    const int t = threadIdx.x;
    const int b = blockIdx.x;
    for (int i = t; i < kHW; i += 256) h[i] = 0;
    __syncthreads();
    const int* bi = flat_idx + b * kM;
    for (int i = t; i < kM; i += 256) atomicAdd(&h[bi[i]], 1);
    __syncthreads();
    int* dst = cnt + b * kHW;
    for (int i = t; i < kHW; i += 256) dst[i] = h[i];
}

// ---------------------------------------------------------------------------
// Kernel 2: fused stream + weighted Gram + stats.
// kKT=16 ping-pong register sets + counted-vmcnt barriers (BAR_SOFT):
// prefetched global loads survive the per-iter barrier, so HBM transfer
// overlaps convert+MFMA continuously.  LDS: 2 bufs x 16KB fragment-order.
// ---------------------------------------------------------------------------
__global__ __launch_bounds__(512, 2) void fused_gram_kernel(
    const float* __restrict__ z, const float* __restrict__ zp,
    const int* __restrict__ cnt,
    float* __restrict__ partial, float* __restrict__ statsPart)
{
    __shared__ char smem[32768];   // buf0 @0 (A 8K | B 8K), buf1 @16K

    const int bx = blockIdx.x;
    const int b = bx & (kB - 1);
    const int win0 = (bx >> 4) * kWin;
    const int t = threadIdx.x;
    const int w = t >> 6, lane = t & 63, l31 = lane & 31, half = lane >> 5;
    const int wr = w >> 2;          // 0..1  row block of 128
    const int wc = w & 3;           // 0..3  col block of 64
    const int rbase = t >> 2;       // 0..127 staging row
    const int cg = t & 3;           // 0..3   staging col group (4 f32)

    const float* zb  = z  + (size_t)b * kD * kHW;
    const float* zpb = zp + (size_t)b * kD * kHW;
    const int* cb = cnt + b * kHW;

    f32x16 acc[4][2];
#pragma unroll
    for (int i = 0; i < 4; ++i)
#pragma unroll
        for (int j = 0; j < 2; ++j)
#pragma unroll
            for (int r = 0; r < 16; ++r) acc[i][j][r] = 0.f;

    float sA[2], ssA[2], sB[2], ssB[2];
#pragma unroll
    for (int q = 0; q < 2; ++q) { sA[q] = ssA[q] = sB[q] = ssB[q] = 0.f; }

    // two register sets (static names -> stay in VGPRs)
    float4 va0[2], vb0[2], va1[2], vb1[2];
    int4 ci0, ci1;

#define LOAD_SET(S, kt)                                                     \
    {                                                                       \
        const int base_ = win0 + (kt) * kKT + cg * 4;                       \
        _Pragma("unroll")                                                   \
        for (int q = 0; q < 2; ++q) {                                       \
            const int row_ = rbase + 128 * q;                               \
            va##S[q] = *(const float4*)(zb  + (size_t)row_ * kHW + base_);  \
            vb##S[q] = *(const float4*)(zpb + (size_t)row_ * kHW + base_);  \
        }                                                                   \
        ci##S = *(const int4*)(cb + base_);                                 \
    }

    // LDS fragment-order write: element (row, k) of A at
    //   As + ((k>>3)*256 + row)*16 + (k&7)*2 ; thread's 4 cols k=cg*4+j
    //   => one 8B write.  B identical at +8KB.
#define CONV_SET(S, buf)                                                    \
    {                                                                       \
        char* As_ = smem + (buf) * 16384;                                   \
        char* Bs_ = As_ + 8192;                                             \
        const float cf_[4] = {(float)ci##S.x, (float)ci##S.y,               \
                              (float)ci##S.z, (float)ci##S.w};              \
        _Pragma("unroll")                                                   \
        for (int q = 0; q < 2; ++q) {                                       \
            const int row_ = rbase + 128 * q;                               \
            const float a_[4]  = {va##S[q].x, va##S[q].y, va##S[q].z, va##S[q].w}; \
            const float bb_[4] = {vb##S[q].x, vb##S[q].y, vb##S[q].z, vb##S[q].w}; \
            ushort4 pa_, pb_;                                               \
            unsigned short* pav_ = (unsigned short*)&pa_;                   \
            unsigned short* pbv_ = (unsigned short*)&pb_;                   \
            _Pragma("unroll")                                               \
            for (int j = 0; j < 4; ++j) {                                   \
                const float a2_ = a_[j] * a_[j];                            \
                const float b2_ = bb_[j] * bb_[j];                          \
                const float wb_ = cf_[j] * bb_[j];                          \
                sA[q] = fmaf(cf_[j], a_[j], sA[q]);                         \
                ssA[q] = fmaf(cf_[j], a2_, ssA[q]);                         \
                sB[q] = fmaf(cf_[j], bb_[j], sB[q]);                        \
                ssB[q] = fmaf(cf_[j], b2_, ssB[q]);                         \
                pav_[j] = f2bf(a_[j]);                                      \
                pbv_[j] = f2bf(wb_);                                        \
            }                                                               \
            const int off_ = (((cg >> 1) * 256 + row_) << 4) + ((cg & 1) << 3); \
            *(unsigned long long*)(As_ + off_) = *(unsigned long long*)&pa_; \
            *(unsigned long long*)(Bs_ + off_) = *(unsigned long long*)&pb_; \
        }                                                                   \
    }

    auto MFMA_STEP = [&](int buf) {
        const char* As = smem + buf * 16384;
        const char* Bs = As + 8192;
        s16x8 af[4], bfr[2];
#pragma unroll
        for (int rt = 0; rt < 4; ++rt) {
            const int row = 128 * wr + 32 * rt + l31;
            af[rt] = *(const s16x8*)(As + ((half * 256 + row) << 4));
        }
#pragma unroll
        for (int ct = 0; ct < 2; ++ct) {
            const int row = 64 * wc + 32 * ct + l31;
            bfr[ct] = *(const s16x8*)(Bs + ((half * 256 + row) << 4));
        }
#pragma unroll
        for (int rt = 0; rt < 4; ++rt)
#pragma unroll
            for (int ct = 0; ct < 2; ++ct)
                acc[rt][ct] = __builtin_amdgcn_mfma_f32_32x32x16_bf16(
                    af[rt], bfr[ct], acc[rt][ct], 0, 0, 0);
    };

    // Prologue: tile0 -> buf0 via S0; preload tile1 (S1), tile2 (S0).
    LOAD_SET(0, 0)
    CONV_SET(0, 0)
    LOAD_SET(1, 1)
    LOAD_SET(0, 2)
    BAR_SOFT();

    // Main loop unrolled x2 (static register-set names).
    for (int kt = 0; kt < kNIter; kt += 2) {
        CONV_SET(1, 1)                       // tile kt+1
        if (kt + 3 < kNIter) LOAD_SET(1, kt + 3)
        MFMA_STEP(0);                        // tile kt
        BAR_SOFT();

        if (kt + 2 < kNIter) CONV_SET(0, 0)  // tile kt+2
        if (kt + 4 < kNIter) LOAD_SET(0, kt + 4)
        MFMA_STEP(1);                        // tile kt+1
        BAR_SOFT();
    }
    __syncthreads();   // full drain once before smem reuse

    // 256x256 partial Gram
    float* out = partial + (size_t)bx * (kD * kD);
#pragma unroll
    for (int rt = 0; rt < 4; ++rt)
#pragma unroll
        for (int ct = 0; ct < 2; ++ct)
#pragma unroll
            for (int r = 0; r < 16; ++r) {
                const int row = 128 * wr + 32 * rt + (r & 3) + 8 * (r >> 2) + 4 * half;
                const int col = 64 * wc + 32 * ct + l31;
                out[row * kD + col] = acc[rt][ct][r];
            }

    // stats partial reduce via (dead) LDS: sd[256 rows][4 cg][4 kinds] = 16KB
    float* sd = (float*)smem;
#pragma unroll
    for (int q = 0; q < 2; ++q) {
        const int row = rbase + 128 * q;
        float* p = sd + (row * 4 + cg) * 4;
        p[0] = sA[q]; p[1] = ssA[q]; p[2] = sB[q]; p[3] = ssB[q];
    }
    __syncthreads();
    {
        const int row = t >> 1;
        const int pair = t & 1;
        float a0 = 0.f, a1 = 0.f;
#pragma unroll
        for (int g = 0; g < 4; ++g) {
            a0 += sd[(row * 4 + g) * 4 + 2 * pair];
            a1 += sd[(row * 4 + g) * 4 + 2 * pair + 1];
        }
        float* p = statsPart + ((size_t)bx * kD + row) * 4;
        p[2 * pair] = a0;
        p[2 * pair + 1] = a1;
    }
#undef LOAD_SET
#undef CONV_SET
}

// ---------------------------------------------------------------------------
// Kernel 3: reduce partial Grams -> G; also reduce statsPart -> statsRed.
// ---------------------------------------------------------------------------
__global__ __launch_bounds__(256) void reduce_gram_kernel(
    const float* __restrict__ partial, const float* __restrict__ statsPart,
    float* __restrict__ G, float* __restrict__ statsRed)
{
    const int d = blockIdx.x;
    const int e = threadIdx.x;
    float s = 0.f;
#pragma unroll 8
    for (int c = 0; c < kNBlk; ++c)
        s += partial[(size_t)c * (kD * kD) + d * kD + e];
    G[d * kD + e] = s;

    // stats: thread e takes source-block e, 4 floats of row d
    const float4 v = *(const float4*)(statsPart + ((size_t)e * kD + d) * 4);
    float x0 = v.x, x1 = v.y, x2 = v.z, x3 = v.w;
#pragma unroll
    for (int o = 32; o; o >>= 1) {
        x0 += __shfl_down(x0, o);
        x1 += __shfl_down(x1, o);
        x2 += __shfl_down(x2, o);
        x3 += __shfl_down(x3, o);
    }
    __shared__ float r[4][4];
    if ((e & 63) == 0) {
        r[e >> 6][0] = x0; r[e >> 6][1] = x1;
        r[e >> 6][2] = x2; r[e >> 6][3] = x3;
    }
    __syncthreads();
    if (e < 4) {
        statsRed[d * 4 + e] = r[0][e] + r[1][e] + r[2][e] + r[3][e];
    }
}

// ---------------------------------------------------------------------------
// Kernel 4: final loss (single block).
// ---------------------------------------------------------------------------
__global__ __launch_bounds__(256) void loss_kernel(
    const float* __restrict__ G, const float* __restrict__ statsRed,
    float* __restrict__ out)
{
    __shared__ float muA[kD], isA[kD], muB[kD], isB[kD];
    const int t = threadIdx.x;
    const float4 v = *(const float4*)(statsRed + t * 4);
    const float n = (float)kN;
    const float mA = v.x / n, mB = v.z / n;
    const float vA = (v.y - n * mA * mA) / (n - 1.f);
    const float vB = (v.w - n * mB * mB) / (n - 1.f);
    const float sdA = fmaxf(sqrtf(fmaxf(vA, 0.f)), 1e-6f);
    const float sdB = fmaxf(sqrtf(fmaxf(vB, 0.f)), 1e-6f);
    muA[t] = mA; isA[t] = 1.f / sdA;
    muB[t] = mB; isB[t] = 1.f / sdB;
    __syncthreads();

    float acc = 0.f;
    for (int d = 0; d < kD; ++d) {
        const int e = t;
        const float c = (G[d * kD + e] / n - muA[d] * muB[e]) * isA[d] * isB[e];
        if (d == e) { const float u = 1.f - c; acc += u * u; }
        else        { acc += kLam * c * c; }
    }
#pragma unroll
    for (int o = 32; o; o >>= 1) acc += __shfl_down(acc, o);
    __shared__ float r[4];
    if ((t & 63) == 0) r[t >> 6] = acc;
    __syncthreads();
    if (t == 0) out[0] = r[0] + r[1] + r[2] + r[3];
}

// ---------------------------------------------------------------------------
extern "C" void kernel_launch(void* const* d_in, const int* in_sizes, int n_in,
                              void* d_out, int out_size, void* d_ws, size_t ws_size,
                              hipStream_t stream) {
    const float* z  = (const float*)d_in[0];
    const float* zp = (const float*)d_in[1];
    const int* flat_idx = (const int*)d_in[2];
    float* out = (float*)d_out;

    char* ws = (char*)d_ws;
    // ws layout:
    //   [0, 1MB)     counts  int [16][16384]
    //   [1MB, 2MB)   statsPart f32 [256][256][4]
    //   [2MB, +4K)   statsRed f32 [256][4]
    //   [2MB+64K, +256K) G f32 [256][256]
    //   [16MB, 80MB) partial f32 [256][256][256]
    int* cnt = (int*)ws;
    float* statsPart = (float*)(ws + (size_t)1 * 1024 * 1024);
    float* statsRed  = (float*)(ws + (size_t)2 * 1024 * 1024);
    float* G = (float*)(ws + (size_t)2 * 1024 * 1024 + 64 * 1024);
    float* partial = (float*)(ws + (size_t)16 * 1024 * 1024);

    count_kernel<<<kB, 256, 0, stream>>>(flat_idx, cnt);
    fused_gram_kernel<<<kNBlk, 512, 0, stream>>>(z, zp, cnt, partial, statsPart);
    reduce_gram_kernel<<<kD, 256, 0, stream>>>(partial, statsPart, G, statsRed);
    loss_kernel<<<1, 256, 0, stream>>>(G, statsRed, out);
}